// Round 6
// baseline (131.126 us; speedup 1.0000x reference)
//
#include <hip/hip_runtime.h>
#include <stdint.h>

#define NLVL 16
#define TSIZE 16384
#define HW 512

__constant__ int c_n[NLVL] = {16,20,25,32,40,50,64,80,101,128,161,203,256,322,406,512};

__device__ __forceinline__ uint32_t pkmax(uint32_t a, uint32_t b) {
    uint32_t r;
    asm("v_pk_max_u16 %0, %1, %2" : "=v"(r) : "v"(a), "v"(b));
    return r;
}

// Sliding window-K max across lanes: lane l -> max(v[l .. l+K-1]).
// log2 doubling + one overlap combine (max is idempotent, overlap is legal).
template<int K>
__device__ __forceinline__ uint32_t slide_max(uint32_t v) {
    uint32_t a = v;
    if constexpr (K >= 2)  a = pkmax(a, (uint32_t)__shfl_down(a, 1, 64));
    if constexpr (K >= 4)  a = pkmax(a, (uint32_t)__shfl_down(a, 2, 64));
    if constexpr (K >= 8)  a = pkmax(a, (uint32_t)__shfl_down(a, 4, 64));
    if constexpr (K >= 16) a = pkmax(a, (uint32_t)__shfl_down(a, 8, 64));
    if constexpr (K >= 32) a = pkmax(a, (uint32_t)__shfl_down(a, 16, 64));
    constexpr int P = K >= 32 ? 32 : K >= 16 ? 16 : K >= 8 ? 8 : K >= 4 ? 4 : K >= 2 ? 2 : 1;
    if constexpr (K != P)  a = pkmax(a, (uint32_t)__shfl_down(a, K - P, 64));
    return a;
}

// One block = one (level, batch, 32x32 output tile).
// poolA: rows of horizontal window-max (stride 33, bank=(r+j)%32); later
//        aliased by feat (float2, 33x33). 2178 dwords covers phase-B's
//        benign over-reads (garbage rows never reach output).
// vmbuf: vertical window-max by (row-pos, col-pos), 33x33.
template<int K>
__device__ __forceinline__ void do_tile(
        const int lvl, const int b, const int tx0, const int ty0,
        const float* __restrict__ x, const float* __restrict__ table,
        float* __restrict__ out,
        uint32_t* poolA, uint32_t* vmbuf) {
    constexpr int gh = 513 - K;
    constexpr float s = (float)gh * (1.0f / 512.0f);   // exact: gh * 2^-9
    const float nf = (float)c_n[lvl];
    const int tid = threadIdx.x;

    float2* feat = reinterpret_cast<float2*>(poolA);   // feat(i,j) = feat[i*33+j]

    const int gy_base = (int)floorf(((float)ty0 + 0.5f) * s - 0.5f);  // may be -1
    const int gx_base = (int)floorf(((float)tx0 + 0.5f) * s - 0.5f);
    const int rmin = max(gy_base, 0);
    const int rmax = min(gy_base + 32, gh - 1);
    const int cmin = max(gx_base, 0);
    const int cmax = min(gx_base + 32, gh - 1);
    const int nr = rmax - rmin;              // valid row positions: 0..nr (<=32)
    const int nc = cmax - cmin;              // valid col positions: 0..nc (<=32)
    const int Rr = nr + K;                   // input rows needed (<=64)

    const float* xb0 = x + (size_t)b * 2 * HW * HW;
    const float* xb1 = xb0 + HW * HW;
    const float2* tb = (const float2*)table + (size_t)lvl * TSIZE;

    if constexpr (K == 1) {
        // pooled grid IS trunc(x*n): gather directly by (clamped) position.
        for (int p = tid; p < 33 * 33; p += 256) {
            const int i = p / 33, j = p - i * 33;
            const int pr = rmin + min(i, nr);
            const int pc = cmin + min(j, nc);
            const uint32_t g0 = (uint32_t)(xb0[pr * HW + pc] * nf);
            const uint32_t g1 = (uint32_t)(xb1[pr * HW + pc] * nf);
            const uint32_t idx = (g0 ^ (g1 * 2654435761u)) & (TSIZE - 1);
            feat[i * 33 + j] = tb[idx];
        }
        __syncthreads();
    } else {
        // ---- phase A: load + pack + horizontal slide-max in registers ----
        {
            const int wv = tid >> 6, lane = tid & 63;
            const int xx = min(cmin + lane, HW - 1);   // clamp only hits unused lanes
            for (int r = wv; r < Rr; r += 4) {
                const int yy = rmin + r;               // <= gh-1+K-1 = 511, in range
                const float v0 = xb0[yy * HW + xx];
                const float v1 = xb1[yy * HW + xx];
                const uint32_t pk = (uint32_t)(v0 * nf) | ((uint32_t)(v1 * nf) << 16);
                const uint32_t m = slide_max<K>(pk);
                if (lane < 33) poolA[r * 33 + lane] = m;   // bank=(r+lane)%32: conflict-free
            }
        }
        __syncthreads();

        // ---- phase B: vertical van Herk (window K), 33 cols x 7 groups x 5 rows ----
        if (tid < 231) {
            const int j  = tid % 33;
            const int g  = tid / 33;
            const int a0 = g * 5;
            uint32_t o0 = 0, o1 = 0, o2 = 0, o3 = 0, o4 = 0;
            if constexpr (K >= 6) {
                const uint32_t s4 = poolA[(a0 + 4) * 33 + j];
                const uint32_t s3 = pkmax(poolA[(a0 + 3) * 33 + j], s4);
                const uint32_t s2 = pkmax(poolA[(a0 + 2) * 33 + j], s3);
                const uint32_t s1 = pkmax(poolA[(a0 + 1) * 33 + j], s2);
                const uint32_t s0 = pkmax(poolA[(a0 + 0) * 33 + j], s1);
                uint32_t run = poolA[(a0 + 5) * 33 + j];
#pragma unroll
                for (int m = 5; m <= K + 3; ++m) {
                    if (m > 5) run = pkmax(run, poolA[(a0 + m) * 33 + j]);
                    if (m == K - 1) o0 = pkmax(s0, run);
                    if (m == K)     o1 = pkmax(s1, run);
                    if (m == K + 1) o2 = pkmax(s2, run);
                    if (m == K + 2) o3 = pkmax(s3, run);
                    if (m == K + 3) o4 = pkmax(s4, run);
                }
            } else {
                uint32_t e[K + 4];
#pragma unroll
                for (int t = 0; t < K + 4; ++t) e[t] = poolA[(a0 + t) * 33 + j];
                uint32_t oo[5];
#pragma unroll
                for (int i = 0; i < 5; ++i) {
                    uint32_t m = e[i];
#pragma unroll
                    for (int t = 1; t < K; ++t) m = pkmax(m, e[i + t]);
                    oo[i] = m;
                }
                o0 = oo[0]; o1 = oo[1]; o2 = oo[2]; o3 = oo[3]; o4 = oo[4];
            }
            vmbuf[(a0 + 0) * 33 + j] = o0;
            vmbuf[(a0 + 1) * 33 + j] = o1;
            vmbuf[(a0 + 2) * 33 + j] = o2;
            if (g < 6) {                       // rows 33,34 don't exist
                vmbuf[(a0 + 3) * 33 + j] = o3;
                vmbuf[(a0 + 4) * 33 + j] = o4;
            }
        }
        __syncthreads();

        // ---- phase C: hash + table gather into feat (clamped positions) ----
        for (int p = tid; p < 33 * 33; p += 256) {
            const int i = p / 33, j = p - i * 33;
            const uint32_t m = vmbuf[min(i, nr) * 33 + min(j, nc)];
            const uint32_t idx = ((m & 0xFFFFu) ^ ((m >> 16) * 2654435761u)) & (TSIZE - 1);
            feat[i * 33 + j] = tb[idx];
        }
        __syncthreads();
    }

    // ---- phase D: bilinear interp from LDS + nontemporal store ----
    const int bty = tid >> 5, btx = tid & 31;
    const int xo = tx0 + btx;
    const float sxf = ((float)xo + 0.5f) * s - 0.5f;
    const float fxf = floorf(sxf);
    const float wx = sxf - fxf;
    const int x0i = (int)fxf;
    const int jx0 = min(max(x0i, 0), gh - 1) - cmin;
    const int jx1 = min(max(x0i + 1, 0), gh - 1) - cmin;
    float* ob = out + ((size_t)b * 32 + lvl * 2) * HW * HW;
    for (int oy = bty; oy < 32; oy += 8) {
        const int y = ty0 + oy;
        const float syf = ((float)y + 0.5f) * s - 0.5f;
        const float fyf = floorf(syf);
        const float wy = syf - fyf;
        const int y0i = (int)fyf;
        const int iy0 = min(max(y0i, 0), gh - 1) - rmin;
        const int iy1 = min(max(y0i + 1, 0), gh - 1) - rmin;
        const float2 f00 = feat[iy0 * 33 + jx0], f01 = feat[iy0 * 33 + jx1];
        const float2 f10 = feat[iy1 * 33 + jx0], f11 = feat[iy1 * 33 + jx1];
        const float w11 = wy * wx;
        const float w10 = wy - w11;
        const float w01 = wx - w11;
        const float w00 = 1.0f - wy - wx + w11;
        const float c0 = f00.x * w00 + f01.x * w01 + f10.x * w10 + f11.x * w11;
        const float c1 = f00.y * w00 + f01.y * w01 + f10.y * w10 + f11.y * w11;
        const size_t o = (size_t)y * HW + xo;
        __builtin_nontemporal_store(c0, &ob[o]);
        __builtin_nontemporal_store(c1, &ob[o + (size_t)HW * HW]);
    }
}

// Grid order: bid = lvl*2048 + tile*8 + b (b fastest -> batch pinned to XCD,
// lvl slowest -> co-resident blocks share code path and x/table locality).
__global__ __launch_bounds__(256) void fused_kernel(
        const float* __restrict__ x, const float* __restrict__ table,
        float* __restrict__ out) {
    __shared__ __align__(16) uint32_t poolA[2178];   // 8712 B (rows + feat alias)
    __shared__ __align__(16) uint32_t vmbuf[33 * 33];// 4356 B

    const int bid  = blockIdx.x;
    const int b    = bid & 7;
    const int tile = (bid >> 3) & 255;
    const int lvl  = bid >> 11;
    const int tx0  = (tile & 15) * 32;
    const int ty0  = (tile >> 4) * 32;

    switch (lvl) {
        case  0: do_tile<32>( 0, b, tx0, ty0, x, table, out, poolA, vmbuf); break;
        case  1: do_tile<25>( 1, b, tx0, ty0, x, table, out, poolA, vmbuf); break;
        case  2: do_tile<20>( 2, b, tx0, ty0, x, table, out, poolA, vmbuf); break;
        case  3: do_tile<16>( 3, b, tx0, ty0, x, table, out, poolA, vmbuf); break;
        case  4: do_tile<12>( 4, b, tx0, ty0, x, table, out, poolA, vmbuf); break;
        case  5: do_tile<10>( 5, b, tx0, ty0, x, table, out, poolA, vmbuf); break;
        case  6: do_tile< 8>( 6, b, tx0, ty0, x, table, out, poolA, vmbuf); break;
        case  7: do_tile< 6>( 7, b, tx0, ty0, x, table, out, poolA, vmbuf); break;
        case  8: do_tile< 5>( 8, b, tx0, ty0, x, table, out, poolA, vmbuf); break;
        case  9: do_tile< 4>( 9, b, tx0, ty0, x, table, out, poolA, vmbuf); break;
        case 10: do_tile< 3>(10, b, tx0, ty0, x, table, out, poolA, vmbuf); break;
        case 11: do_tile< 2>(11, b, tx0, ty0, x, table, out, poolA, vmbuf); break;
        case 12: do_tile< 2>(12, b, tx0, ty0, x, table, out, poolA, vmbuf); break;
        case 13: do_tile< 1>(13, b, tx0, ty0, x, table, out, poolA, vmbuf); break;
        case 14: do_tile< 1>(14, b, tx0, ty0, x, table, out, poolA, vmbuf); break;
        default: do_tile< 1>(15, b, tx0, ty0, x, table, out, poolA, vmbuf); break;
    }
}

extern "C" void kernel_launch(void* const* d_in, const int* in_sizes, int n_in,
                              void* d_out, int out_size, void* d_ws, size_t ws_size,
                              hipStream_t stream) {
    const float* x     = (const float*)d_in[0];
    const float* table = (const float*)d_in[1];
    float* out         = (float*)d_out;
    (void)d_ws; (void)ws_size;

    fused_kernel<<<dim3(NLVL * 256 * 8), dim3(256), 0, stream>>>(x, table, out);
}

// Round 7
// 124.232 us; speedup vs baseline: 1.0555x; 1.0555x over previous
//
#include <hip/hip_runtime.h>
#include <stdint.h>

#define NLVL 16
#define TSIZE 16384
#define HW 512

__constant__ int c_n[NLVL] = {16,20,25,32,40,50,64,80,101,128,161,203,256,322,406,512};

__device__ __forceinline__ uint32_t pkmax(uint32_t a, uint32_t b) {
    uint32_t r;
    asm("v_pk_max_u16 %0, %1, %2" : "=v"(r) : "v"(a), "v"(b));
    return r;
}

// One block = one (level, batch, 32x32 output tile). LDS layout (dwords):
//   S  [0,4096)     staged packed trunc(x*n), row-major [64][64], LINEAR
//   V  [4096,6272)  vertical window-max [34][64] (row 33 = overread pad)
//   Hm [0,1188)     2D pooled result [33][36]   (aliases dead S)
//   F4 [1200,5556)  pair-duplicated feat float4 [33][33] (aliases dead S/V)
// Vertical pass: lane = column -> every LDS access is a row access of a
// linear tile: conflict-free, no swizzle, no bpermute.
template<int K>
__device__ __forceinline__ void do_tile(
        const int lvl, const int b, const int tx0, const int ty0,
        const float* __restrict__ x, const float* __restrict__ table,
        float* __restrict__ out, uint32_t* lds) {
    constexpr int gh = 513 - K;
    constexpr float s = (float)gh * (1.0f / 512.0f);   // exact: gh * 2^-9
    const float nf = (float)c_n[lvl];
    const int tid = threadIdx.x;

    const float* xb0 = x + (size_t)b * 2 * HW * HW;
    const float* xb1 = xb0 + HW * HW;
    const float2* tb = (const float2*)table + (size_t)lvl * TSIZE;
    float* ob = out + ((size_t)b * 32 + lvl * 2) * HW * HW;

    if constexpr (K == 1) {
        // gh == 512 -> s == 1.0 -> half-pixel bilinear is the IDENTITY map:
        // out[y][x] = table[hash(trunc(x*n))]. No pooling, no LDS.
        const int btx = tid & 31, bty = tid >> 5;
        const int xo = tx0 + btx;
        for (int oy = bty; oy < 32; oy += 8) {
            const int y = ty0 + oy;
            const float v0 = xb0[y * HW + xo];
            const float v1 = xb1[y * HW + xo];
            const uint32_t g0 = (uint32_t)(v0 * nf);
            const uint32_t g1 = (uint32_t)(v1 * nf);
            const uint32_t idx = (g0 ^ (g1 * 2654435761u)) & (TSIZE - 1);
            const float2 f = tb[idx];
            const size_t o = (size_t)y * HW + xo;
            __builtin_nontemporal_store(f.x, &ob[o]);
            __builtin_nontemporal_store(f.y, &ob[o + (size_t)HW * HW]);
        }
        return;
    }

    uint32_t* S  = lds;
    uint32_t* V  = lds + 4096;
    uint32_t* Hm = lds;
    float4*   F4 = (float4*)(lds + 1200);

    const int gy_base = (int)floorf(((float)ty0 + 0.5f) * s - 0.5f);  // may be -1
    const int gx_base = (int)floorf(((float)tx0 + 0.5f) * s - 0.5f);
    const int rmin = max(gy_base, 0);
    const int cmin = max(gx_base, 0);
    const int nr = min(gy_base + 32, gh - 1) - rmin;   // valid row offsets 0..nr
    const int nc = min(gx_base + 32, gh - 1) - cmin;   // valid col offsets 0..nc
    const int Rr = nr + K;                             // staged rows (<=64)

    // ---- P1: stage packed trunc(x*n), linear [64][64] ----
    {
        const int wv = tid >> 6, c = tid & 63;
        const int xx = min(cmin + c, HW - 1);          // clamp hits only unused cols
        for (int r = wv; r < Rr; r += 4) {
            const int yy = rmin + r;                   // <= gh-1+K-1 = 511
            const float v0 = xb0[yy * HW + xx];
            const float v1 = xb1[yy * HW + xx];
            S[r * 64 + c] = (uint32_t)(v0 * nf) | ((uint32_t)(v1 * nf) << 16);
        }
    }
    __syncthreads();

    // ---- P2: vertical window-max (van Herk), lane = column ----
    // Thread (c, g): outputs rows 9g..9g+8 (i<=32). All reads are row-reads
    // of linear S: conflict-free. Over-reads past Rr feed only i>nr outputs,
    // which are never consumed.
    {
        const int c = tid & 63, g = tid >> 6;
        const int R0 = 9 * g;
        const uint32_t* col = S + R0 * 64 + c;
        uint32_t e[K + 8];
#pragma unroll
        for (int t = 0; t < K + 8; ++t) e[t] = col[t * 64];
        uint32_t o[9];
        if constexpr (K >= 10) {
            uint32_t sfx[9];
            sfx[8] = e[8];
#pragma unroll
            for (int t = 7; t >= 0; --t) sfx[t] = pkmax(e[t], sfx[t + 1]);
            uint32_t run = e[9];
#pragma unroll
            for (int m = 9; m <= K + 7; ++m) {
                if (m > 9) run = pkmax(run, e[m]);
                if (m >= K - 1) o[m - K + 1] = pkmax(sfx[m - K + 1], run);
            }
        } else {
#pragma unroll
            for (int i = 0; i < 9; ++i) {
                uint32_t m = e[i];
#pragma unroll
                for (int t = 1; t < K; ++t) m = pkmax(m, e[i + t]);
                o[i] = m;
            }
        }
#pragma unroll
        for (int t = 0; t < 9; ++t) {
            const int i = R0 + t;
            if (i <= 32) V[i * 64 + c] = o[t];
        }
    }
    __syncthreads();

    // ---- P3: horizontal window-max (van Herk) on 33 rows, b128 chunks ----
    if (tid < 132) {
        const int i = tid >> 2, g = tid & 3;
        if (g < 3) {
            constexpr int NE  = 12 + K - 1;
            constexpr int NCH = (NE + 3) >> 2;
            uint32_t f[NCH * 4];
            const uint4* rp = (const uint4*)(V + i * 64 + 12 * g);  // 16B aligned
#pragma unroll
            for (int cc = 0; cc < NCH; ++cc) {
                const uint4 q = rp[cc];
                f[4*cc] = q.x; f[4*cc+1] = q.y; f[4*cc+2] = q.z; f[4*cc+3] = q.w;
            }
            uint32_t wm[12];
            if constexpr (K >= 13) {
                uint32_t sfx[12];
                sfx[11] = f[11];
#pragma unroll
                for (int d = 10; d >= 0; --d) sfx[d] = pkmax(f[d], sfx[d + 1]);
                uint32_t run = f[12];
#pragma unroll
                for (int m = 12; m <= K + 10; ++m) {
                    if (m > 12) run = pkmax(run, f[m]);
                    if (m >= K - 1) wm[m - K + 1] = pkmax(sfx[m - K + 1], run);
                }
            } else {
#pragma unroll
                for (int d = 0; d < 12; ++d) {
                    uint32_t m = f[d];
#pragma unroll
                    for (int t = 1; t < K; ++t) m = pkmax(m, f[d + t]);
                    wm[d] = m;
                }
            }
            uint32_t* hw_ = Hm + i * 36 + 12 * g;
            ((uint4*)hw_)[0] = make_uint4(wm[0], wm[1], wm[2],  wm[3]);
            ((uint4*)hw_)[1] = make_uint4(wm[4], wm[5], wm[6],  wm[7]);
            ((uint4*)hw_)[2] = make_uint4(wm[8], wm[9], wm[10], wm[11]);
        }
    }
    __syncthreads();

    // ---- P4: hash + table gather + pair-duplicated feat write ----
    // F4[i][j] = (feat[i][j], feat[i][j+1]); col jj clamped to nc so the
    // duplicated .zw at the clamp edge replicates the edge value.
    for (int p = tid; p < 33 * 34; p += 256) {
        const int i = p / 34, jj = p - i * 34;
        const uint32_t m = Hm[i * 36 + min(jj, nc)];
        const uint32_t idx = ((m & 0xFFFFu) ^ ((m >> 16) * 2654435761u)) & (TSIZE - 1);
        const float2 v = tb[idx];
        float2* Fp = (float2*)(F4 + i * 33);
        if (jj < 33) Fp[2 * jj] = v;          // .xy of col jj
        if (jj >= 1) Fp[2 * jj - 1] = v;      // .zw of col jj-1
    }
    __syncthreads();

    // ---- P5: bilinear interp (2 x b128 per pixel) + nontemporal store ----
    const int bty = tid >> 5, btx = tid & 31;
    const int xo = tx0 + btx;
    const float sxf = ((float)xo + 0.5f) * s - 0.5f;
    const float fxf = floorf(sxf);
    const float wx = sxf - fxf;
    const int x0i = (int)fxf;
    const int jx0 = min(max(x0i, 0), gh - 1) - cmin;   // in [0, nc]
    const bool xclamp = (x0i < 0);                     // xo==0 on edge tiles
    for (int oy = bty; oy < 32; oy += 8) {
        const int y = ty0 + oy;
        const float syf = ((float)y + 0.5f) * s - 0.5f;
        const float fyf = floorf(syf);
        const float wy = syf - fyf;
        const int y0i = (int)fyf;
        const int iy0 = min(max(y0i, 0), gh - 1) - rmin;
        const int iy1 = min(max(y0i + 1, 0), gh - 1) - rmin;  // clamps row edge
        float4 a  = F4[iy0 * 33 + jx0];    // (f00, f01)
        float4 bq = F4[iy1 * 33 + jx0];    // (f10, f11)
        if (xclamp) { a.z = a.x; a.w = a.y; bq.z = bq.x; bq.w = bq.y; }
        const float w11 = wy * wx;
        const float w10 = wy - w11;
        const float w01 = wx - w11;
        const float w00 = 1.0f - wy - wx + w11;
        const float c0 = a.x * w00 + a.z * w01 + bq.x * w10 + bq.z * w11;
        const float c1 = a.y * w00 + a.w * w01 + bq.y * w10 + bq.w * w11;
        const size_t o = (size_t)y * HW + xo;
        __builtin_nontemporal_store(c0, &ob[o]);
        __builtin_nontemporal_store(c1, &ob[o + (size_t)HW * HW]);
    }
}

// Grid order: bid = lvl*2048 + tile*8 + b (b fastest -> batch pinned to XCD,
// lvl slowest -> co-resident blocks share code path and x/table locality).
__global__ __launch_bounds__(256, 6) void fused_kernel(
        const float* __restrict__ x, const float* __restrict__ table,
        float* __restrict__ out) {
    __shared__ __align__(16) uint32_t lds[6272];   // 25088 B

    const int bid  = blockIdx.x;
    const int b    = bid & 7;
    const int tile = (bid >> 3) & 255;
    const int lvl  = bid >> 11;
    const int tx0  = (tile & 15) * 32;
    const int ty0  = (tile >> 4) * 32;

    switch (lvl) {
        case  0: do_tile<32>( 0, b, tx0, ty0, x, table, out, lds); break;
        case  1: do_tile<25>( 1, b, tx0, ty0, x, table, out, lds); break;
        case  2: do_tile<20>( 2, b, tx0, ty0, x, table, out, lds); break;
        case  3: do_tile<16>( 3, b, tx0, ty0, x, table, out, lds); break;
        case  4: do_tile<12>( 4, b, tx0, ty0, x, table, out, lds); break;
        case  5: do_tile<10>( 5, b, tx0, ty0, x, table, out, lds); break;
        case  6: do_tile< 8>( 6, b, tx0, ty0, x, table, out, lds); break;
        case  7: do_tile< 6>( 7, b, tx0, ty0, x, table, out, lds); break;
        case  8: do_tile< 5>( 8, b, tx0, ty0, x, table, out, lds); break;
        case  9: do_tile< 4>( 9, b, tx0, ty0, x, table, out, lds); break;
        case 10: do_tile< 3>(10, b, tx0, ty0, x, table, out, lds); break;
        case 11: do_tile< 2>(11, b, tx0, ty0, x, table, out, lds); break;
        case 12: do_tile< 2>(12, b, tx0, ty0, x, table, out, lds); break;
        case 13: do_tile< 1>(13, b, tx0, ty0, x, table, out, lds); break;
        case 14: do_tile< 1>(14, b, tx0, ty0, x, table, out, lds); break;
        default: do_tile< 1>(15, b, tx0, ty0, x, table, out, lds); break;
    }
}

extern "C" void kernel_launch(void* const* d_in, const int* in_sizes, int n_in,
                              void* d_out, int out_size, void* d_ws, size_t ws_size,
                              hipStream_t stream) {
    const float* x     = (const float*)d_in[0];
    const float* table = (const float*)d_in[1];
    float* out         = (float*)d_out;
    (void)d_ws; (void)ws_size;

    fused_kernel<<<dim3(NLVL * 256 * 8), dim3(256), 0, stream>>>(x, table, out);
}

// Round 8
// 110.239 us; speedup vs baseline: 1.1895x; 1.1269x over previous
//
#include <hip/hip_runtime.h>
#include <stdint.h>

#define NLVL 16
#define TSIZE 16384
#define HW 512

__constant__ int c_n[NLVL] = {16,20,25,32,40,50,64,80,101,128,161,203,256,322,406,512};

__device__ __forceinline__ uint32_t pkmax(uint32_t a, uint32_t b) {
    uint32_t r;
    asm("v_pk_max_u16 %0, %1, %2" : "=v"(r) : "v"(a), "v"(b));
    return r;
}

// One block = one (level, batch, 32x32 output tile). LDS (17952 B total):
//   V    [33][68] u32  : vertical window-max (stride 68 -> phase-B b128 base
//                        bank = (4i+12g)%32 varies with i: ~2-way max)
//   feat [33][34] f2   : gathered features
// Phase A loads global->registers per wave (NO LDS staging) and does the
// vertical van Herk in registers; phase B does horizontal van Herk + hash +
// gather in one pass. 2 barriers total.
template<int K>
__device__ __forceinline__ void do_tile(
        const int lvl, const int b, const int tx0, const int ty0,
        const float* __restrict__ x, const float* __restrict__ table,
        float* __restrict__ out, uint32_t* lds) {
    constexpr int gh = 513 - K;
    constexpr float s = (float)gh * (1.0f / 512.0f);   // exact: gh * 2^-9
    const float nf = (float)c_n[lvl];
    const int tid = threadIdx.x;

    const float* xb0 = x + (size_t)b * 2 * HW * HW;
    const float* xb1 = xb0 + HW * HW;
    const float2* tb = (const float2*)table + (size_t)lvl * TSIZE;
    float* ob = out + ((size_t)b * 32 + lvl * 2) * HW * HW;

    if constexpr (K == 1) {
        // gh == 512 -> s == 1.0 -> bilinear is the identity map.
        const int btx = tid & 31, bty = tid >> 5;
        const int xo = tx0 + btx;
        for (int oy = bty; oy < 32; oy += 8) {
            const int y = ty0 + oy;
            const uint32_t g0 = (uint32_t)(xb0[y * HW + xo] * nf);
            const uint32_t g1 = (uint32_t)(xb1[y * HW + xo] * nf);
            const uint32_t idx = (g0 ^ (g1 * 2654435761u)) & (TSIZE - 1);
            const float2 f = tb[idx];
            const size_t o = (size_t)y * HW + xo;
            __builtin_nontemporal_store(f.x, &ob[o]);
            __builtin_nontemporal_store(f.y, &ob[o + (size_t)HW * HW]);
        }
        return;
    }

    uint32_t* V   = lds;                          // [33][68]
    float2*  feat = (float2*)(lds + 33 * 68);     // [33][34]

    const int gy_base = (int)floorf(((float)ty0 + 0.5f) * s - 0.5f);  // may be -1
    const int gx_base = (int)floorf(((float)tx0 + 0.5f) * s - 0.5f);
    const int rmin = max(gy_base, 0);
    const int cmin = max(gx_base, 0);

    // ---- phase A: global->reg load + vertical van Herk, lane = column ----
    // Wave w produces V rows 8w..8w+8 (rows 8,16,24 duplicated: same value).
    // Input rows beyond the valid range clamp to 511; they only feed V rows
    // i>nr which are never consumed downstream.
    {
        const int wv = tid >> 6, c = tid & 63;
        const int r0 = 8 * wv;
        const int xx = min(cmin + c, HW - 1);      // clamp hits only unused cols
        const int ybase = rmin + r0;
        uint32_t e[K + 8];
#pragma unroll
        for (int t = 0; t < K + 8; ++t) {
            const int yy = min(ybase + t, HW - 1);
            const float v0 = xb0[yy * HW + xx];
            const float v1 = xb1[yy * HW + xx];
            e[t] = (uint32_t)(v0 * nf) | ((uint32_t)(v1 * nf) << 16);
        }
        uint32_t o[9];
        if constexpr (K >= 10) {
            uint32_t sfx[9];
            sfx[8] = e[8];
#pragma unroll
            for (int t = 7; t >= 0; --t) sfx[t] = pkmax(e[t], sfx[t + 1]);
            uint32_t run = e[9];
#pragma unroll
            for (int m = 9; m <= K + 7; ++m) {
                if (m > 9) run = pkmax(run, e[m]);
                if (m >= K - 1) o[m - K + 1] = pkmax(sfx[m - K + 1], run);
            }
        } else {
#pragma unroll
            for (int i = 0; i < 9; ++i) {
                uint32_t m = e[i];
#pragma unroll
                for (int t = 1; t < K; ++t) m = pkmax(m, e[i + t]);
                o[i] = m;
            }
        }
#pragma unroll
        for (int t = 0; t < 9; ++t) V[(r0 + t) * 68 + c] = o[t];  // bank (4i+c)%32: 2-way
    }
    __syncthreads();

    // ---- phase B: horizontal van Herk + hash + gather, 33 rows x 3 groups ----
    if (tid < 99) {
        const int i = tid / 3, g = tid % 3;
        constexpr int NE  = 12 + K - 1;
        constexpr int NCH = (NE + 3) >> 2;         // b128 chunks (fits: 24+4*NCH<=68)
        uint32_t f[NCH * 4];
        const uint4* rp = (const uint4*)(V + i * 68 + 12 * g);   // 16B aligned
#pragma unroll
        for (int cc = 0; cc < NCH; ++cc) {
            const uint4 q = rp[cc];
            f[4*cc] = q.x; f[4*cc+1] = q.y; f[4*cc+2] = q.z; f[4*cc+3] = q.w;
        }
        uint32_t wm[12];
        if constexpr (K >= 13) {
            uint32_t sfx[12];
            sfx[11] = f[11];
#pragma unroll
            for (int d = 10; d >= 0; --d) sfx[d] = pkmax(f[d], sfx[d + 1]);
            uint32_t run = f[12];
#pragma unroll
            for (int m = 12; m <= K + 10; ++m) {
                if (m > 12) run = pkmax(run, f[m]);
                if (m >= K - 1) wm[m - K + 1] = pkmax(sfx[m - K + 1], run);
            }
        } else {
#pragma unroll
            for (int d = 0; d < 12; ++d) {
                uint32_t m = f[d];
#pragma unroll
                for (int t = 1; t < K; ++t) m = pkmax(m, f[d + t]);
                wm[d] = m;
            }
        }
#pragma unroll
        for (int d = 0; d < 12; ++d) {
            const int j = 12 * g + d;
            if (j < 33) {
                const uint32_t m = wm[d];
                const uint32_t idx = ((m & 0xFFFFu) ^ ((m >> 16) * 2654435761u)) & (TSIZE - 1);
                feat[i * 34 + j] = tb[idx];
            }
        }
    }
    __syncthreads();

    // ---- phase C: bilinear interp + nontemporal store ----
    const int bty = tid >> 5, btx = tid & 31;
    const int xo = tx0 + btx;
    const float sxf = ((float)xo + 0.5f) * s - 0.5f;
    const float fxf = floorf(sxf);
    const float wx = sxf - fxf;
    const int x0i = (int)fxf;
    const int jx0 = min(max(x0i, 0), gh - 1) - cmin;
    const int jx1 = min(max(x0i + 1, 0), gh - 1) - cmin;
    for (int oy = bty; oy < 32; oy += 8) {
        const int y = ty0 + oy;
        const float syf = ((float)y + 0.5f) * s - 0.5f;
        const float fyf = floorf(syf);
        const float wy = syf - fyf;
        const int y0i = (int)fyf;
        const int iy0 = min(max(y0i, 0), gh - 1) - rmin;
        const int iy1 = min(max(y0i + 1, 0), gh - 1) - rmin;
        const float2 f00 = feat[iy0 * 34 + jx0], f01 = feat[iy0 * 34 + jx1];
        const float2 f10 = feat[iy1 * 34 + jx0], f11 = feat[iy1 * 34 + jx1];
        const float w11 = wy * wx;
        const float w10 = wy - w11;
        const float w01 = wx - w11;
        const float w00 = 1.0f - wy - wx + w11;
        const float c0 = f00.x * w00 + f01.x * w01 + f10.x * w10 + f11.x * w11;
        const float c1 = f00.y * w00 + f01.y * w01 + f10.y * w10 + f11.y * w11;
        const size_t o = (size_t)y * HW + xo;
        __builtin_nontemporal_store(c0, &ob[o]);
        __builtin_nontemporal_store(c1, &ob[o + (size_t)HW * HW]);
    }
}

// Grid order: bid = lvl*2048 + tile*8 + b (b fastest -> batch pinned to XCD,
// lvl slowest -> co-resident blocks share code path and x/table locality).
__global__ __launch_bounds__(256) void fused_kernel(
        const float* __restrict__ x, const float* __restrict__ table,
        float* __restrict__ out) {
    __shared__ __align__(16) uint32_t lds[33 * 68 + 33 * 34 * 2];  // 17952 B

    const int bid  = blockIdx.x;
    const int b    = bid & 7;
    const int tile = (bid >> 3) & 255;
    const int lvl  = bid >> 11;
    const int tx0  = (tile & 15) * 32;
    const int ty0  = (tile >> 4) * 32;

    switch (lvl) {
        case  0: do_tile<32>( 0, b, tx0, ty0, x, table, out, lds); break;
        case  1: do_tile<25>( 1, b, tx0, ty0, x, table, out, lds); break;
        case  2: do_tile<20>( 2, b, tx0, ty0, x, table, out, lds); break;
        case  3: do_tile<16>( 3, b, tx0, ty0, x, table, out, lds); break;
        case  4: do_tile<12>( 4, b, tx0, ty0, x, table, out, lds); break;
        case  5: do_tile<10>( 5, b, tx0, ty0, x, table, out, lds); break;
        case  6: do_tile< 8>( 6, b, tx0, ty0, x, table, out, lds); break;
        case  7: do_tile< 6>( 7, b, tx0, ty0, x, table, out, lds); break;
        case  8: do_tile< 5>( 8, b, tx0, ty0, x, table, out, lds); break;
        case  9: do_tile< 4>( 9, b, tx0, ty0, x, table, out, lds); break;
        case 10: do_tile< 3>(10, b, tx0, ty0, x, table, out, lds); break;
        case 11: do_tile< 2>(11, b, tx0, ty0, x, table, out, lds); break;
        case 12: do_tile< 2>(12, b, tx0, ty0, x, table, out, lds); break;
        case 13: do_tile< 1>(13, b, tx0, ty0, x, table, out, lds); break;
        case 14: do_tile< 1>(14, b, tx0, ty0, x, table, out, lds); break;
        default: do_tile< 1>(15, b, tx0, ty0, x, table, out, lds); break;
    }
}

extern "C" void kernel_launch(void* const* d_in, const int* in_sizes, int n_in,
                              void* d_out, int out_size, void* d_ws, size_t ws_size,
                              hipStream_t stream) {
    const float* x     = (const float*)d_in[0];
    const float* table = (const float*)d_in[1];
    float* out         = (float*)d_out;
    (void)d_ws; (void)ws_size;

    fused_kernel<<<dim3(NLVL * 256 * 8), dim3(256), 0, stream>>>(x, table, out);
}

// Round 10
// 109.013 us; speedup vs baseline: 1.2028x; 1.0112x over previous
//
#include <hip/hip_runtime.h>
#include <stdint.h>

#define NLVL 16
#define TSIZE 16384
#define HW 512

typedef float vfloat4 __attribute__((ext_vector_type(4)));  // native vec for nt-store

__constant__ int c_n[NLVL] = {16,20,25,32,40,50,64,80,101,128,161,203,256,322,406,512};

__device__ __forceinline__ uint32_t pkmax(uint32_t a, uint32_t b) {
    uint32_t r;
    asm("v_pk_max_u16 %0, %1, %2" : "=v"(r) : "v"(a), "v"(b));
    return r;
}

// One block = one (level, batch, 32x32 output tile). LDS (17952 B):
//   V    [33][68] u32 : vertical window-max (stride 68 -> ~2-way banks)
//   feat [33][34] f2  : gathered features
// Phase A: global->reg + vertical van Herk (no LDS staging).
// Phase B: horizontal van Herk + hash + DEDUP'd gather (runs of equal max
//          share one table load; iid data => runs ~K/2 long).
template<int K>
__device__ __forceinline__ void do_tile(
        const int lvl, const int b, const int tx0, const int ty0,
        const float* __restrict__ x, const float* __restrict__ table,
        float* __restrict__ out, uint32_t* lds) {
    constexpr int gh = 513 - K;
    constexpr float s = (float)gh * (1.0f / 512.0f);   // exact: gh * 2^-9
    const float nf = (float)c_n[lvl];
    const int tid = threadIdx.x;

    const float* xb0 = x + (size_t)b * 2 * HW * HW;
    const float* xb1 = xb0 + HW * HW;
    const float2* tb = (const float2*)table + (size_t)lvl * TSIZE;
    float* ob = out + ((size_t)b * 32 + lvl * 2) * HW * HW;

    if constexpr (K == 1) {
        // gh == 512 -> s == 1.0 -> bilinear is the identity map.
        // Thread owns a 1x4 strip: float4 loads, vec4 nontemporal stores.
        const int oy = tid >> 3, xo = tx0 + (tid & 7) * 4;
        const int y = ty0 + oy;
        const float4 v0 = *(const float4*)&xb0[y * HW + xo];
        const float4 v1 = *(const float4*)&xb1[y * HW + xo];
        vfloat4 o0, o1;
        {
            const uint32_t i0 = (((uint32_t)(v0.x * nf)) ^ (((uint32_t)(v1.x * nf)) * 2654435761u)) & (TSIZE - 1);
            const uint32_t i1 = (((uint32_t)(v0.y * nf)) ^ (((uint32_t)(v1.y * nf)) * 2654435761u)) & (TSIZE - 1);
            const uint32_t i2 = (((uint32_t)(v0.z * nf)) ^ (((uint32_t)(v1.z * nf)) * 2654435761u)) & (TSIZE - 1);
            const uint32_t i3 = (((uint32_t)(v0.w * nf)) ^ (((uint32_t)(v1.w * nf)) * 2654435761u)) & (TSIZE - 1);
            const float2 f0 = tb[i0], f1 = tb[i1], f2 = tb[i2], f3 = tb[i3];
            o0 = (vfloat4){f0.x, f1.x, f2.x, f3.x};
            o1 = (vfloat4){f0.y, f1.y, f2.y, f3.y};
        }
        const size_t o = (size_t)y * HW + xo;
        __builtin_nontemporal_store(o0, (vfloat4*)&ob[o]);
        __builtin_nontemporal_store(o1, (vfloat4*)&ob[o + (size_t)HW * HW]);
        return;
    }

    uint32_t* V   = lds;                          // [33][68]
    float2*  feat = (float2*)(lds + 33 * 68);     // [33][34]

    const int gy_base = (int)floorf(((float)ty0 + 0.5f) * s - 0.5f);  // may be -1
    const int gx_base = (int)floorf(((float)tx0 + 0.5f) * s - 0.5f);
    const int rmin = max(gy_base, 0);
    const int cmin = max(gx_base, 0);

    // ---- phase A: global->reg load + vertical van Herk, lane = column ----
    {
        const int wv = tid >> 6, c = tid & 63;
        const int r0 = 8 * wv;
        const int xx = min(cmin + c, HW - 1);      // clamp hits only unused cols
        const int ybase = rmin + r0;
        uint32_t e[K + 8];
#pragma unroll
        for (int t = 0; t < K + 8; ++t) {
            const int yy = min(ybase + t, HW - 1);
            const float v0 = xb0[yy * HW + xx];
            const float v1 = xb1[yy * HW + xx];
            e[t] = (uint32_t)(v0 * nf) | ((uint32_t)(v1 * nf) << 16);
        }
        uint32_t o[9];
        if constexpr (K >= 10) {
            uint32_t sfx[9];
            sfx[8] = e[8];
#pragma unroll
            for (int t = 7; t >= 0; --t) sfx[t] = pkmax(e[t], sfx[t + 1]);
            uint32_t run = e[9];
#pragma unroll
            for (int m = 9; m <= K + 7; ++m) {
                if (m > 9) run = pkmax(run, e[m]);
                if (m >= K - 1) o[m - K + 1] = pkmax(sfx[m - K + 1], run);
            }
        } else {
#pragma unroll
            for (int i = 0; i < 9; ++i) {
                uint32_t m = e[i];
#pragma unroll
                for (int t = 1; t < K; ++t) m = pkmax(m, e[i + t]);
                o[i] = m;
            }
        }
#pragma unroll
        for (int t = 0; t < 9; ++t) V[(r0 + t) * 68 + c] = o[t];
    }
    __syncthreads();

    // ---- phase B: horizontal van Herk + hash + dedup'd gather ----
    if (tid < 99) {
        const int i = tid / 3, g = tid % 3;
        constexpr int NE  = 12 + K - 1;
        constexpr int NCH = (NE + 3) >> 2;
        uint32_t f[NCH * 4];
        const uint4* rp = (const uint4*)(V + i * 68 + 12 * g);   // 16B aligned
#pragma unroll
        for (int cc = 0; cc < NCH; ++cc) {
            const uint4 q = rp[cc];
            f[4*cc] = q.x; f[4*cc+1] = q.y; f[4*cc+2] = q.z; f[4*cc+3] = q.w;
        }
        uint32_t wm[12];
        if constexpr (K >= 13) {
            uint32_t sfx[12];
            sfx[11] = f[11];
#pragma unroll
            for (int d = 10; d >= 0; --d) sfx[d] = pkmax(f[d], sfx[d + 1]);
            uint32_t run = f[12];
#pragma unroll
            for (int m = 12; m <= K + 10; ++m) {
                if (m > 12) run = pkmax(run, f[m]);
                if (m >= K - 1) wm[m - K + 1] = pkmax(sfx[m - K + 1], run);
            }
        } else {
#pragma unroll
            for (int d = 0; d < 12; ++d) {
                uint32_t m = f[d];
#pragma unroll
                for (int t = 1; t < K; ++t) m = pkmax(m, f[d + t]);
                wm[d] = m;
            }
        }
        uint32_t prev = 0xFFFFFFFFu;
        float2 v = make_float2(0.0f, 0.0f);
#pragma unroll
        for (int d = 0; d < 12; ++d) {
            const int j = 12 * g + d;
            if (j < 33) {
                const uint32_t m = wm[d];
                const uint32_t idx = ((m & 0xFFFFu) ^ ((m >> 16) * 2654435761u)) & (TSIZE - 1);
                if (idx != prev) { v = tb[idx]; prev = idx; }   // masked-off lanes skip TA
                feat[i * 34 + j] = v;
            }
        }
    }
    __syncthreads();

    // ---- phase C: bilinear interp + nontemporal store ----
    const int bty = tid >> 5, btx = tid & 31;
    const int xo = tx0 + btx;
    const float sxf = ((float)xo + 0.5f) * s - 0.5f;
    const float fxf = floorf(sxf);
    const float wx = sxf - fxf;
    const int x0i = (int)fxf;
    const int jx0 = min(max(x0i, 0), gh - 1) - cmin;
    const int jx1 = min(max(x0i + 1, 0), gh - 1) - cmin;
    for (int oy = bty; oy < 32; oy += 8) {
        const int y = ty0 + oy;
        const float syf = ((float)y + 0.5f) * s - 0.5f;
        const float fyf = floorf(syf);
        const float wy = syf - fyf;
        const int y0i = (int)fyf;
        const int iy0 = min(max(y0i, 0), gh - 1) - rmin;
        const int iy1 = min(max(y0i + 1, 0), gh - 1) - rmin;
        const float2 f00 = feat[iy0 * 34 + jx0], f01 = feat[iy0 * 34 + jx1];
        const float2 f10 = feat[iy1 * 34 + jx0], f11 = feat[iy1 * 34 + jx1];
        const float w11 = wy * wx;
        const float w10 = wy - w11;
        const float w01 = wx - w11;
        const float w00 = 1.0f - wy - wx + w11;
        const float c0 = f00.x * w00 + f01.x * w01 + f10.x * w10 + f11.x * w11;
        const float c1 = f00.y * w00 + f01.y * w01 + f10.y * w10 + f11.y * w11;
        const size_t o = (size_t)y * HW + xo;
        __builtin_nontemporal_store(c0, &ob[o]);
        __builtin_nontemporal_store(c1, &ob[o + (size_t)HW * HW]);
    }
}

// Grid order: bid = lvl*2048 + tile*8 + b (b fastest -> batch pinned to XCD,
// lvl slowest -> co-resident blocks share code path and x/table locality).
__global__ __launch_bounds__(256) void fused_kernel(
        const float* __restrict__ x, const float* __restrict__ table,
        float* __restrict__ out) {
    __shared__ __align__(16) uint32_t lds[33 * 68 + 33 * 34 * 2];  // 17952 B

    const int bid  = blockIdx.x;
    const int b    = bid & 7;
    const int tile = (bid >> 3) & 255;
    const int lvl  = bid >> 11;
    const int tx0  = (tile & 15) * 32;
    const int ty0  = (tile >> 4) * 32;

    switch (lvl) {
        case  0: do_tile<32>( 0, b, tx0, ty0, x, table, out, lds); break;
        case  1: do_tile<25>( 1, b, tx0, ty0, x, table, out, lds); break;
        case  2: do_tile<20>( 2, b, tx0, ty0, x, table, out, lds); break;
        case  3: do_tile<16>( 3, b, tx0, ty0, x, table, out, lds); break;
        case  4: do_tile<12>( 4, b, tx0, ty0, x, table, out, lds); break;
        case  5: do_tile<10>( 5, b, tx0, ty0, x, table, out, lds); break;
        case  6: do_tile< 8>( 6, b, tx0, ty0, x, table, out, lds); break;
        case  7: do_tile< 6>( 7, b, tx0, ty0, x, table, out, lds); break;
        case  8: do_tile< 5>( 8, b, tx0, ty0, x, table, out, lds); break;
        case  9: do_tile< 4>( 9, b, tx0, ty0, x, table, out, lds); break;
        case 10: do_tile< 3>(10, b, tx0, ty0, x, table, out, lds); break;
        case 11: do_tile< 2>(11, b, tx0, ty0, x, table, out, lds); break;
        case 12: do_tile< 2>(12, b, tx0, ty0, x, table, out, lds); break;
        case 13: do_tile< 1>(13, b, tx0, ty0, x, table, out, lds); break;
        case 14: do_tile< 1>(14, b, tx0, ty0, x, table, out, lds); break;
        default: do_tile< 1>(15, b, tx0, ty0, x, table, out, lds); break;
    }
}

extern "C" void kernel_launch(void* const* d_in, const int* in_sizes, int n_in,
                              void* d_out, int out_size, void* d_ws, size_t ws_size,
                              hipStream_t stream) {
    const float* x     = (const float*)d_in[0];
    const float* table = (const float*)d_in[1];
    float* out         = (float*)d_out;
    (void)d_ws; (void)ws_size;

    fused_kernel<<<dim3(NLVL * 256 * 8), dim3(256), 0, stream>>>(x, table, out);
}